// Round 10
// baseline (391.828 us; speedup 1.0000x reference)
//
#include <hip/hip_runtime.h>
#include <cstdint>
#include <cstddef>
#include <cmath>

typedef unsigned short u16;
typedef short v8s __attribute__((ext_vector_type(8)));
typedef float v4f __attribute__((ext_vector_type(4)));

constexpr int SEQ = 4096;
constexpr int FEAT = 2048;
constexpr int F3 = 6144;

// ---------- helpers ----------

__device__ __forceinline__ u16 f2bf(float f) {
  union { float f; uint32_t u; } v; v.f = f;
  uint32_t r = v.u + 0x7FFFu + ((v.u >> 16) & 1u);  // round-to-nearest-even
  return (u16)(r >> 16);
}

__device__ __forceinline__ float bf2f(u16 s) {
  union { uint32_t u; float f; } v; v.u = ((uint32_t)s) << 16;
  return v.f;
}

// async global->LDS, 16B per lane; lds dest is wave-uniform base (HW: base+lane*16)
__device__ __forceinline__ void gld_lds16(const u16* g, u16* l) {
  __builtin_amdgcn_global_load_lds(
      (const __attribute__((address_space(1))) void*)g,
      (__attribute__((address_space(3))) void*)l, 16, 0, 0);
}

// ---------- conversion / transpose / combine ----------

__global__ void cvt_f32_bf16(const float* __restrict__ in, u16* __restrict__ out, int n8) {
  int i = blockIdx.x * 256 + threadIdx.x;
  if (i >= n8) return;
  const float4* p = (const float4*)in + (size_t)i * 2;
  float4 a = p[0], b = p[1];
  union { u16 s[8]; uint4 v; } u;
  u.s[0] = f2bf(a.x); u.s[1] = f2bf(a.y); u.s[2] = f2bf(a.z); u.s[3] = f2bf(a.w);
  u.s[4] = f2bf(b.x); u.s[5] = f2bf(b.y); u.s[6] = f2bf(b.z); u.s[7] = f2bf(b.w);
  *(uint4*)(out + (size_t)i * 8) = u.v;
}

__global__ void transp_f2b(const float* __restrict__ in, int ldin,
                           u16* __restrict__ out, int ldout) {
  __shared__ float tile[32][33];
  int c0 = blockIdx.x * 32, r0 = blockIdx.y * 32;
  int tx = threadIdx.x, ty = threadIdx.y;
#pragma unroll
  for (int p = 0; p < 4; ++p)
    tile[ty + 8 * p][tx] = in[(size_t)(r0 + ty + 8 * p) * ldin + c0 + tx];
  __syncthreads();
#pragma unroll
  for (int p = 0; p < 4; ++p)
    out[(size_t)(c0 + ty + 8 * p) * ldout + r0 + tx] = f2bf(tile[tx][ty + 8 * p]);
}

__global__ void transp_b2b(const u16* __restrict__ in, int ldin,
                           u16* __restrict__ out, int ldout) {
  __shared__ u16 tile[32][33];
  int c0 = blockIdx.x * 32, r0 = blockIdx.y * 32;
  int tx = threadIdx.x, ty = threadIdx.y;
#pragma unroll
  for (int p = 0; p < 4; ++p)
    tile[ty + 8 * p][tx] = in[(size_t)(r0 + ty + 8 * p) * ldin + c0 + tx];
  __syncthreads();
#pragma unroll
  for (int p = 0; p < 4; ++p)
    out[(size_t)(c0 + ty + 8 * p) * ldout + r0 + tx] = tile[tx][ty + 8 * p];
}

// out = a + b (fp32, float4-vectorized): combines att@v split-K partials
__global__ __launch_bounds__(256) void add2_f32(
    const float* __restrict__ a, const float* __restrict__ b,
    float* __restrict__ o, int n4) {
  int i = blockIdx.x * 256 + threadIdx.x;
  if (i >= n4) return;
  float4 x = ((const float4*)a)[i], y = ((const float4*)b)[i];
  x.x += y.x; x.y += y.y; x.z += y.z; x.w += y.w;
  ((float4*)o)[i] = x;
}

// ---------- gemmw: C[M,N] = A[M,K] * B[N,K]^T  (bf16 in, k contiguous) ----------
// r4-proven structure (~115 us on GEMM1, ~910 TF). Tile 128(M)x256(N), BK=32,
// 256 thr = 4 waves; each wave owns 128x64 (reuse 42.7 FLOP/LDS-byte).
// LDS: single region [buf][A 128x32 | B 256x32] = 24 KiB x 3 bufs = 72 KiB
// -> 2 blocks/CU (8 waves), __launch_bounds__(256,2).
// Phase (one 32-K tile): STAGE(t+2, 6 gld_lds16/thread) | LOADA (8 ds) |
//   32 MFMA (bf preloaded) | vmcnt(6) | s_barrier | LOADB(t+1)->regs.
// Race-safety (verified r3/r4): vmcnt(6) pre-barrier leaves only this
// phase's 6 stages in flight => post-barrier, tile t+1 fully in LDS for all
// waves; STAGE(t+2) overwrites tile t-1's buffer whose last reads drained
// before their wave crossed BAR(t-1).
// LDS swizzle (proven, conflicts=0): row of 32 elems = 4 chunks of 16B;
// logical chunk c at physical (c + (row>>1))&3; global source pre-rotated.
// MODE: 0 = rect grid (XCD col-major swizzle if SWZ: same-XCD share B panel);
//       1 = att@v: 512-block grid, split-K z=2 into CONTIGUOUS disjoint fp32
//           partials (Cv + z*SEQ*FEAT floats, plain stores, no atomics).
//           r10 pairing: depth class par = (f&1)^((f>>3)&1), p=(f>>4)&15,
//           z=f>>8, bi = par ? p : 31-p, bj = ((f>>1)&3)|(((f>>3)&1)<<2).
//           Under BOTH (f,f+1) and (f,f+8) CU-co-location, par flips with
//           p,z fixed -> every co-resident pair = deep(31-p)+shallow(p) =
//           66 phases exactly. (r9's desc/asc halves assumed stride-256
//           co-location; measured 84us == the (f,f+1)/(f,f+8) worst case,
//           ruling stride-256 out.)

#define BARW() asm volatile("s_barrier" ::: "memory")
#define VMC6() asm volatile("s_waitcnt vmcnt(6)" ::: "memory")
#define LGKM0() asm volatile("s_waitcnt lgkmcnt(0)" ::: "memory")

#define STAGE(SB, KO) do { \
  u16* Lb = &LDSU[SB][0] + w * 512; \
  gld_lds16(pA0 + (KO), Lb); \
  gld_lds16(pA0 + (size_t)64 * LDA_ + (KO), Lb + 2048); \
  gld_lds16(pB0 + (KO), Lb + 4096); \
  gld_lds16(pB0 + (size_t)64 * LDB_ + (KO), Lb + 4096 + 2048); \
  gld_lds16(pB0 + (size_t)128 * LDB_ + (KO), Lb + 4096 + 4096); \
  gld_lds16(pB0 + (size_t)192 * LDB_ + (KO), Lb + 4096 + 6144); \
} while (0)

#define LOADA(BUF) do { _Pragma("unroll") \
  for (int mi = 0; mi < 8; ++mi) \
    af[mi] = *(const v8s*)(&LDSU[BUF][0] + (mi * 16 + lm) * 32 + lqs); \
} while (0)

#define LOADB(BUF) do { _Pragma("unroll") \
  for (int ni = 0; ni < 4; ++ni) \
    bf4[ni] = *(const v8s*)(&LDSU[BUF][0] + 4096 + (w * 64 + ni * 16 + lm) * 32 + lqs); \
} while (0)

template<int LDA_, int LDB_, int LDC_, int OUTMODE /*0=bf16 store, 1=fp32 store*/,
         int ADDB, int MODE, int SWZ>
__global__ __launch_bounds__(256, 2) void gemmw(
    const u16* __restrict__ A, const u16* __restrict__ B,
    void* __restrict__ Cv, int K,
    const float* __restrict__ bias, float scale) {
  int bi, bj, ks, ke;
  if (MODE == 1) {
    // att@v grid, 512 blocks: pairwise-complementary under (f,f+1) & (f,f+8)
    const int f = blockIdx.x;
    const int d3 = (f >> 3) & 1;
    const int par = (f & 1) ^ d3;    // 0 = deep, 1 = shallow
    const int p = (f >> 4) & 15;
    const int z = f >> 8;
    bi = par ? p : 31 - p;
    bj = ((f >> 1) & 3) | (d3 << 2);
    const int kq = (bi + 1) * 64;
    ks = z ? kq : 0;  ke = ks + kq;  // nt = 2*(bi+1), even, >= 2
    Cv = (void*)((float*)Cv + (size_t)z * SEQ * FEAT);  // contiguous partial z
  } else {
    if (SWZ) {
      // column-major within XCD chunk: same-XCD neighbors share the B panel
      const int gx = gridDim.x, gy = gridDim.y;
      const int b = blockIdx.y * gx + blockIdx.x;
      const int cpx = (gx * gy) >> 3;            // nwg % 8 == 0
      const int s = (b & 7) * cpx + (b >> 3);
      bi = s % gy;  bj = s / gy;
    } else { bj = blockIdx.x; bi = blockIdx.y; }
    ks = 0; ke = K;
  }
  const int i0 = bi * 128, j0 = bj * 256;

  // [buf][ A: 128 rows x 32 (4096 elems) | B: 256 rows x 32 (8192 elems) ]
  __shared__ u16 LDSU[3][12288];   // 72 KiB

  const int t = threadIdx.x;
  const int w = t >> 6, l = t & 63;
  const int lm = l & 15, lq = l >> 4;
  // fragment read: physical chunk = (lq + (row>>1)) & 3; row bases are
  // multiples of 8 => (row>>1)&3 == (lm>>1)&3
  const int lqs = ((lq + (lm >> 1)) & 3) * 8;

  // staging: wave w handles instrs covering 16-row groups; lane l: row =
  // base + (l>>2), physical chunk l&3, logical = ((l&3)-((row>>1)&3))&3.
  const int rA = w * 16 + (l >> 2);
  const int cA = ((((l & 3) - ((rA >> 1) & 3)) & 3)) * 8;
  const u16* pA0 = A + (size_t)(i0 + rA) * LDA_ + cA;
  const u16* pB0 = B + (size_t)(j0 + rA) * LDB_ + cA;

  v4f acc[8][4];
#pragma unroll
  for (int a = 0; a < 8; ++a)
#pragma unroll
    for (int b2 = 0; b2 < 4; ++b2)
      acc[a][b2] = v4f{0.f, 0.f, 0.f, 0.f};

  v8s af[8], bf4[4];

  // prologue: stage tiles 0 (buf0) and 1 (buf1); vmcnt(6) -> tile0 landed
  STAGE(0, ks); STAGE(1, ks + 32);
  VMC6(); BARW();
  LOADB(0);                           // B fragments of tile 0 -> regs

  const int nt = (ke - ks) >> 5;      // even, >= 2 in all modes
  int b0 = 0, b1 = 1;
  for (int tt = 0; tt < nt; tt += 2) {
    const int kc = ks + (tt << 5);
    const int s2 = 3 - b0 - b1;       // the third buffer
    // sub-phase 0: compute tile tt (A in b0, B preloaded in bf4)
    {
      const int kst = (kc + 64 < ke) ? kc + 64 : ks;   // A+B tile tt+2
      STAGE(s2, kst);
      LOADA(b0);
      __builtin_amdgcn_s_setprio(1);
#pragma unroll
      for (int mi = 0; mi < 8; ++mi)
#pragma unroll
        for (int ni = 0; ni < 4; ++ni)
          acc[mi][ni] = __builtin_amdgcn_mfma_f32_16x16x32_bf16(af[mi], bf4[ni], acc[mi][ni], 0, 0, 0);
      __builtin_amdgcn_s_setprio(0);
      VMC6(); BARW();                 // tile tt+1 landed (all waves)
      LOADB(b1);                      // B fragments of tile tt+1 -> regs
    }
    // sub-phase 1: compute tile tt+1 (A in b1)
    {
      const int kst = (kc + 96 < ke) ? kc + 96 : ks;   // tile tt+3 (clamped)
      STAGE(b0, kst);
      LOADA(b1);
      __builtin_amdgcn_s_setprio(1);
#pragma unroll
      for (int mi = 0; mi < 8; ++mi)
#pragma unroll
        for (int ni = 0; ni < 4; ++ni)
          acc[mi][ni] = __builtin_amdgcn_mfma_f32_16x16x32_bf16(af[mi], bf4[ni], acc[mi][ni], 0, 0, 0);
      __builtin_amdgcn_s_setprio(0);
      VMC6(); BARW();                 // tile tt+2 landed
      LOADB(s2);                      // B fragments of tile tt+2 -> regs
    }
    b1 = b0; b0 = s2;                 // bufs advance by 2 tiles
  }

  // epilogue: C/D layout col=lane&15, row=quad*4+reg [m89-verified]
#pragma unroll
  for (int mi = 0; mi < 8; ++mi) {
#pragma unroll
    for (int ni = 0; ni < 4; ++ni) {
      const int cc = j0 + w * 64 + ni * 16 + lm;
      const float badd = ADDB ? bias[cc] : 0.f;
#pragma unroll
      for (int r = 0; r < 4; ++r) {
        const int rr = i0 + mi * 16 + lq * 4 + r;
        if (OUTMODE == 0)
          ((u16*)Cv)[(size_t)rr * LDC_ + cc] = f2bf(acc[mi][ni][r] * scale + badd);
        else
          ((float*)Cv)[(size_t)rr * LDC_ + cc] = acc[mi][ni][r];
      }
    }
  }
}

#undef STAGE
#undef LOADA
#undef LOADB

// ---------- gemm8tri: 256x256 8-phase GEMM on a flat triangular grid ----------
// r1/r7-verified schedule deployed where its 1-block/CU occupancy is free:
// GEMM2's 136-block grid (0.53 rounds -> makespan = ONE block-time).
// C[M,N] = A[M,K]*B[N,K]^T, bf16, 512 thr = 8 waves (2Mx4N), wave owns 128x64,
// BK=64, double-buffered LDS 128 KiB, K % 128 == 0.
// Per K-tile: 4 quadrant phases; 1 half-tile (2 x gld_lds16) staged per phase;
// counted vmcnt(6) ONLY at phases 4/8; raw s_barrier (no drain).
// LDS swizzle: row of 64 elems = 8 chunks of 16B, logical chunk c at physical
// (c + row) & 7; global source pre-rotated (both-sides rule).

#define LDA8(BUF, MH) do { _Pragma("unroll") \
  for (int fi = 0; fi < 4; ++fi) { \
    const u16* ap = &As8[BUF][wr][(MH) * 4096 + fi * 1024]; \
    af[fi][0] = *(const v8s*)(ap + off0); \
    af[fi][1] = *(const v8s*)(ap + off1); \
  } } while (0)

#define LDB8(BUF) do { _Pragma("unroll") \
  for (int ni = 0; ni < 4; ++ni) { \
    const u16* bp = &Bs8[BUF][bh][bo + ni * 1024]; \
    bfr[ni][0] = *(const v8s*)(bp + off0); \
    bfr[ni][1] = *(const v8s*)(bp + off1); \
  } } while (0)

#define MMA8(MH, NL) do { _Pragma("unroll") \
  for (int fi = 0; fi < 4; ++fi) { _Pragma("unroll") \
    for (int nn = 0; nn < 2; ++nn) { \
      acc[(MH)*4+fi][(NL)+nn] = __builtin_amdgcn_mfma_f32_16x16x32_bf16( \
          af[fi][0], bfr[(NL)+nn][0], acc[(MH)*4+fi][(NL)+nn], 0, 0, 0); \
      acc[(MH)*4+fi][(NL)+nn] = __builtin_amdgcn_mfma_f32_16x16x32_bf16( \
          af[fi][1], bfr[(NL)+nn][1], acc[(MH)*4+fi][(NL)+nn], 0, 0, 0); \
    } } } while (0)

#define STG8A(BUF, H, KO) do { \
  gld_lds16(Ag + (size_t)(H) * 128 * LDA_ + (KO), &As8[BUF][H][w8 * 1024]); \
  gld_lds16(Ag + ((size_t)(H) * 128 + 8) * LDA_ + (KO), &As8[BUF][H][w8 * 1024 + 512]); \
  } while (0)

#define STG8B(BUF, H, KO) do { \
  gld_lds16(Bg + (size_t)(H) * 128 * LDB_ + (KO), &Bs8[BUF][H][w8 * 1024]); \
  gld_lds16(Bg + ((size_t)(H) * 128 + 8) * LDB_ + (KO), &Bs8[BUF][H][w8 * 1024 + 512]); \
  } while (0)

template<int LDA_, int LDB_, int LDC_>
__global__ __launch_bounds__(512, 2) void gemm8tri(
    const u16* __restrict__ A, const u16* __restrict__ B,
    u16* __restrict__ C, int K, float scale) {
  // flat lower-triangular grid (bj <= bi), XCD-chunked; gridDim.x % 8 == 0
  const int b = blockIdx.x;
  const int cpx = (int)gridDim.x >> 3;
  const int s = (b & 7) * cpx + (b >> 3);
  int bi = (int)((sqrtf(8.f * s + 1.f) - 1.f) * 0.5f);
  while ((bi + 1) * (bi + 2) / 2 <= s) ++bi;
  while (bi * (bi + 1) / 2 > s) --bi;
  const int bj = s - bi * (bi + 1) / 2;
  const int i0 = bi * 256, j0 = bj * 256;

  __shared__ u16 As8[2][2][8192];  // [buf][half][128*64], 64 KiB
  __shared__ u16 Bs8[2][2][8192];  // 64 KiB

  const int t = threadIdx.x;
  const int w8 = t >> 6, l = t & 63;
  const int wr = w8 >> 2, wc = w8 & 3;
  const int lm = l & 15, lq = l >> 4;
  const int bh = wc >> 1, bo = (wc & 1) * 4096;

  // fragment-read offsets within a half (chunk rotation, conflicts=0 r1)
  const int off0 = lm * 64 + ((lq + lm) & 7) * 8;        // s=0
  const int off1 = lm * 64 + ((lq + lm + 4) & 7) * 8;    // s=1

  // staging: row = w8*16 + (l>>3); logical col chunk = ((l&7) - (l>>3)) & 7
  const int srow = w8 * 16 + (l >> 3);
  const int scol = (((l & 7) - (l >> 3)) & 7) * 8;
  const u16* Ag = A + (size_t)(i0 + srow) * LDA_ + scol;
  const u16* Bg = B + (size_t)(j0 + srow) * LDB_ + scol;

  v4f acc[8][4];
#pragma unroll
  for (int a = 0; a < 8; ++a)
#pragma unroll
    for (int b2 = 0; b2 < 4; ++b2)
      acc[a][b2] = v4f{0.f, 0.f, 0.f, 0.f};

  v8s af[4][2], bfr[4][2];

  // prologue: tile0 -> buf0 (B0,B1,A0,A1), tile1 -> buf1 (B0,B1,A0).
  // 14 loads; vmcnt(6) -> oldest 8 (all of buf0) landed.
  STG8B(0, 0, 0); STG8B(0, 1, 0); STG8A(0, 0, 0); STG8A(0, 1, 0);
  STG8B(1, 0, 64); STG8B(1, 1, 64); STG8A(1, 0, 64);
  VMC6(); BARW();

  const int nit = K >> 7;  // K % 128 == 0
  for (int it = 0; it < nit; ++it) {
    const int kc = it << 7;
    const int k1 = kc + 64;                     // tile 2it+1 (always valid)
    int k2 = kc + 128; if (k2 >= K) k2 = 0;     // clamped stages never read
    int k3 = kc + 192; if (k3 >= K) k3 = 0;

    // P1: Q(m0, n0..1) on buf0
    LDA8(0, 0); LDB8(0);
    STG8A(1, 1, k1);
    BARW(); LGKM0();
    __builtin_amdgcn_s_setprio(1); MMA8(0, 0); __builtin_amdgcn_s_setprio(0);
    BARW();
    // P2: Q(m0, n2..3)
    STG8B(0, 0, k2);
    BARW();
    __builtin_amdgcn_s_setprio(1); MMA8(0, 2); __builtin_amdgcn_s_setprio(0);
    BARW();
    // P3: Q(m1, n0..1)
    LDA8(0, 1);
    STG8B(0, 1, k2);
    BARW(); LGKM0();
    __builtin_amdgcn_s_setprio(1); MMA8(1, 0); __builtin_amdgcn_s_setprio(0);
    BARW();
    // P4: Q(m1, n2..3); counted wait -> buf1 fully landed before P5
    STG8A(0, 0, k2);
    BARW();
    __builtin_amdgcn_s_setprio(1); MMA8(1, 2); __builtin_amdgcn_s_setprio(0);
    VMC6(); BARW();
    // P5: Q(m0, n0..1) on buf1
    LDA8(1, 0); LDB8(1);
    STG8A(0, 1, k2);
    BARW(); LGKM0();
    __builtin_amdgcn_s_setprio(1); MMA8(0, 0); __builtin_amdgcn_s_setprio(0);
    BARW();
    // P6: Q(m0, n2..3)
    STG8B(1, 0, k3);
    BARW();
    __builtin_amdgcn_s_setprio(1); MMA8(0, 2); __builtin_amdgcn_s_setprio(0);
    BARW();
    // P7: Q(m1, n0..1)
    LDA8(1, 1);
    STG8B(1, 1, k3);
    BARW(); LGKM0();
    __builtin_amdgcn_s_setprio(1); MMA8(1, 0); __builtin_amdgcn_s_setprio(0);
    BARW();
    // P8: Q(m1, n2..3); counted wait -> buf0 fully landed before next P1
    STG8A(1, 0, k3);
    BARW();
    __builtin_amdgcn_s_setprio(1); MMA8(1, 2); __builtin_amdgcn_s_setprio(0);
    VMC6(); BARW();
  }

  // epilogue: C/D layout col=lane&15, row=quad*4+reg [m89-verified]
#pragma unroll
  for (int mi = 0; mi < 8; ++mi) {
#pragma unroll
    for (int ni = 0; ni < 4; ++ni) {
      const int cc = j0 + wc * 64 + ni * 16 + lm;
#pragma unroll
      for (int r = 0; r < 4; ++r) {
        const int rr = i0 + wr * 128 + mi * 16 + lq * 4 + r;
        C[(size_t)rr * LDC_ + cc] = f2bf(acc[mi][ni][r] * scale);
      }
    }
  }
}

#undef LDA8
#undef LDB8
#undef MMA8
#undef STG8A
#undef STG8B

// ---------- row softmax with causal + padding mask (single bf16 input) ----------
// r10: both passes vectorized (uint4 = 8 bf16 per load; were scalar, G13)
__global__ __launch_bounds__(256) void softmax_rows(
    const u16* __restrict__ S0,
    u16* __restrict__ att, const int* __restrict__ npad_p) {
  const int i = blockIdx.x;
  const int np = *npad_p;
  const int kend = ((i >> 7) + 1) << 7;   // 128-rounded: matches attV read range
  const u16* r0 = S0 + (size_t)i * SEQ;
  u16* arow = att + (size_t)i * SEQ;
  const int t = threadIdx.x;

  float m = -3.0e38f, s = 0.f;
  for (int j0b = t * 8; j0b < kend; j0b += 2048) {
    union { u16 s8[8]; uint4 v; } ui;
    ui.v = *(const uint4*)(r0 + j0b);
#pragma unroll
    for (int q = 0; q < 8; ++q) {
      const int j = j0b + q;
      if (j >= np && j <= i) {
        const float v = bf2f(ui.s8[q]);
        if (v > m) { s = s * __expf(m - v) + 1.f; m = v; }
        else       { s += __expf(v - m); }
      }
    }
  }
#pragma unroll
  for (int off = 32; off > 0; off >>= 1) {
    float mo = __shfl_xor(m, off);
    float so = __shfl_xor(s, off);
    float M = fmaxf(m, mo);
    s = s * __expf(m - M) + so * __expf(mo - M);
    m = M;
  }
  __shared__ float sm[4], ss[4];
  const int w = t >> 6, l = t & 63;
  if (l == 0) { sm[w] = m; ss[w] = s; }
  __syncthreads();
  const float M = fmaxf(fmaxf(sm[0], sm[1]), fmaxf(sm[2], sm[3]));
  const float Ssum = ss[0] * __expf(sm[0] - M) + ss[1] * __expf(sm[1] - M) +
                     ss[2] * __expf(sm[2] - M) + ss[3] * __expf(sm[3] - M);
  const float inv = 1.f / Ssum;  // padded rows masked to 0 below; inv unused there

  for (int j0b = t * 8; j0b < kend; j0b += 2048) {
    union { u16 s8[8]; uint4 v; } ui, uo;
    ui.v = *(const uint4*)(r0 + j0b);
#pragma unroll
    for (int q = 0; q < 8; ++q) {
      const int j = j0b + q;
      float a = 0.f;
      if (j >= np && j <= i)
        a = __expf(bf2f(ui.s8[q]) - M) * inv;
      uo.s8[q] = f2bf(a);
    }
    *(uint4*)(arow + j0b) = uo.v;
  }
}

// ---------- launch ----------

extern "C" void kernel_launch(void* const* d_in, const int* in_sizes, int n_in,
                              void* d_out, int out_size, void* d_ws, size_t ws_size,
                              hipStream_t stream) {
  const float* x = (const float*)d_in[0];
  const float* W = (const float*)d_in[1];
  const float* b = (const float*)d_in[2];
  const int* npad = (const int*)d_in[3];
  float* out = (float*)d_out;

  // workspace (168 MB, same footprint as the r0 baseline):
  // [xb 16MB | Wt 24MB] reused as att 32MB ][ qkvb 48MB ][ vt 16MB ]
  // [ sc0 32MB -> p0 ][ sc1 32MB -> p1 ]   (p0/p1 CONTIGUOUS: kernel offsets
  //                                         partial z by z*SEQ*FEAT floats)
  char* p = (char*)d_ws;
  u16* xb = (u16*)p;
  u16* Wt = (u16*)(p + (size_t)SEQ * FEAT * 2);
  u16* att = (u16*)p;
  p += (size_t)SEQ * FEAT * 2 + (size_t)F3 * FEAT * 2;
  u16* qkvb = (u16*)p;  p += (size_t)SEQ * F3 * 2;
  u16* vt   = (u16*)p;  p += (size_t)FEAT * SEQ * 2;
  u16* sc0  = (u16*)p;  p += (size_t)SEQ * SEQ * 2;   // bf16 scores -> fp32 p0
  p += (size_t)SEQ * SEQ * 2;                         // fp32 p1 (contiguous)
  if (ws_size < (size_t)(p - (char*)d_ws)) return;

  float* p0 = (float*)sc0;                    // partial z=0 (32MB)
  float* p1 = p0 + (size_t)SEQ * FEAT;        // partial z=1 (next 32MB)

  const float scale = 0.02209708691207961f;  // 1/sqrt(2048)

  cvt_f32_bf16<<<SEQ * FEAT / 8 / 256, 256, 0, stream>>>(x, xb, SEQ * FEAT / 8);
  transp_f2b<<<dim3(F3 / 32, FEAT / 32), dim3(32, 8), 0, stream>>>(W, F3, Wt, FEAT);
  // qkv = x @ W + b: 128x256 tiles, grid 24x32 = 768 blocks (2 blocks/CU)
  gemmw<FEAT, FEAT, F3, 0, 1, 0, 1><<<dim3(F3 / 256, SEQ / 128), 256, 0, stream>>>(
      xb, Wt, (void*)qkvb, FEAT, b, 1.0f);
  transp_b2b<<<dim3(FEAT / 32, SEQ / 32), dim3(32, 8), 0, stream>>>(
      qkvb + 2 * FEAT, F3, vt, SEQ);
  // scores = (q @ k^T)/sqrt(F): 8-phase 256^2, flat triangular grid 16*17/2 =
  // 136 blocks (1 block/CU, 0.53 rounds -> makespan = one block-time)
  gemm8tri<F3, F3, SEQ><<<dim3(136), 512, 0, stream>>>(
      qkvb, qkvb + FEAT, sc0, FEAT, scale);
  softmax_rows<<<SEQ, 256, 0, stream>>>(sc0, att, npad);
  // out = att @ v: split-K z=2 -> contiguous disjoint fp32 partials p0/p1
  // (plain stores, no atomics); pairwise-complementary block indexing ->
  // 66 phases per co-resident pair under (f,f+1) and (f,f+8) co-location
  gemmw<SEQ, SEQ, FEAT, 1, 0, 1, 0><<<dim3(512), 256, 0, stream>>>(
      att, vt, (void*)p0, 0, nullptr, 1.0f);
  // out = p0 + p1
  add2_f32<<<SEQ * FEAT / 4 / 256, 256, 0, stream>>>(p0, p1, out, SEQ * FEAT / 4);
}

// Round 11
// 376.188 us; speedup vs baseline: 1.0416x; 1.0416x over previous
//
#include <hip/hip_runtime.h>
#include <cstdint>
#include <cstddef>
#include <cmath>

typedef unsigned short u16;
typedef short v8s __attribute__((ext_vector_type(8)));
typedef float v4f __attribute__((ext_vector_type(4)));

constexpr int SEQ = 4096;
constexpr int FEAT = 2048;
constexpr int F3 = 6144;

// ---------- helpers ----------

__device__ __forceinline__ u16 f2bf(float f) {
  union { float f; uint32_t u; } v; v.f = f;
  uint32_t r = v.u + 0x7FFFu + ((v.u >> 16) & 1u);  // round-to-nearest-even
  return (u16)(r >> 16);
}

__device__ __forceinline__ float bf2f(u16 s) {
  union { uint32_t u; float f; } v; v.u = ((uint32_t)s) << 16;
  return v.f;
}

// async global->LDS, 16B per lane; lds dest is wave-uniform base (HW: base+lane*16)
__device__ __forceinline__ void gld_lds16(const u16* g, u16* l) {
  __builtin_amdgcn_global_load_lds(
      (const __attribute__((address_space(1))) void*)g,
      (__attribute__((address_space(3))) void*)l, 16, 0, 0);
}

// ---------- conversion / transpose / combine ----------

__global__ void cvt_f32_bf16(const float* __restrict__ in, u16* __restrict__ out, int n8) {
  int i = blockIdx.x * 256 + threadIdx.x;
  if (i >= n8) return;
  const float4* p = (const float4*)in + (size_t)i * 2;
  float4 a = p[0], b = p[1];
  union { u16 s[8]; uint4 v; } u;
  u.s[0] = f2bf(a.x); u.s[1] = f2bf(a.y); u.s[2] = f2bf(a.z); u.s[3] = f2bf(a.w);
  u.s[4] = f2bf(b.x); u.s[5] = f2bf(b.y); u.s[6] = f2bf(b.z); u.s[7] = f2bf(b.w);
  *(uint4*)(out + (size_t)i * 8) = u.v;
}

__global__ void transp_f2b(const float* __restrict__ in, int ldin,
                           u16* __restrict__ out, int ldout) {
  __shared__ float tile[32][33];
  int c0 = blockIdx.x * 32, r0 = blockIdx.y * 32;
  int tx = threadIdx.x, ty = threadIdx.y;
#pragma unroll
  for (int p = 0; p < 4; ++p)
    tile[ty + 8 * p][tx] = in[(size_t)(r0 + ty + 8 * p) * ldin + c0 + tx];
  __syncthreads();
#pragma unroll
  for (int p = 0; p < 4; ++p)
    out[(size_t)(c0 + ty + 8 * p) * ldout + r0 + tx] = f2bf(tile[tx][ty + 8 * p]);
}

__global__ void transp_b2b(const u16* __restrict__ in, int ldin,
                           u16* __restrict__ out, int ldout) {
  __shared__ u16 tile[32][33];
  int c0 = blockIdx.x * 32, r0 = blockIdx.y * 32;
  int tx = threadIdx.x, ty = threadIdx.y;
#pragma unroll
  for (int p = 0; p < 4; ++p)
    tile[ty + 8 * p][tx] = in[(size_t)(r0 + ty + 8 * p) * ldin + c0 + tx];
  __syncthreads();
#pragma unroll
  for (int p = 0; p < 4; ++p)
    out[(size_t)(c0 + ty + 8 * p) * ldout + r0 + tx] = tile[tx][ty + 8 * p];
}

// out = p0 + p1 (att@v window partials). Rows < 2048 have NO p0 contribution
// (only window1 writes them, into p1) -> skip the p0 read; no memset needed.
__global__ __launch_bounds__(256) void add2_f32(
    const float* __restrict__ a, const float* __restrict__ b,
    float* __restrict__ o, int n4) {
  int i = blockIdx.x * 256 + threadIdx.x;
  if (i >= n4) return;
  float4 y = ((const float4*)b)[i];
  if (i >= 2048 * (FEAT / 4)) {            // rows >= 2048: both partials
    float4 x = ((const float4*)a)[i];
    y.x += x.x; y.y += x.y; y.z += x.z; y.w += x.w;
  }
  ((float4*)o)[i] = y;
}

// ---------- gemmw: C[M,N] = A[M,K] * B[N,K]^T  (bf16 in, k contiguous) ----------
// r4-proven structure (~113 us on GEMM1, ~910 TF). Tile 128(M)x256(N), BK=32,
// 256 thr = 4 waves; each wave owns 128x64 (reuse 42.7 FLOP/LDS-byte).
// LDS: single region [buf][A 128x32 | B 256x32] = 24 KiB x 3 bufs = 72 KiB,
// __launch_bounds__(256,2).
// Phase (one 32-K tile): STAGE(t+2, 6 gld_lds16/thread) | LOADA (8 ds) |
//   32 MFMA (bf preloaded) | vmcnt(6) | s_barrier | LOADB(t+1)->regs.
// Race-safety (verified r3/r4): vmcnt(6) pre-barrier leaves only this
// phase's 6 stages in flight => post-barrier, tile t+1 fully in LDS for all
// waves; STAGE(t+2) overwrites tile t-1's buffer whose last reads drained
// before their wave crossed BAR(t-1).
// LDS swizzle (proven, conflicts=0): row of 32 elems = 4 chunks of 16B;
// logical chunk c at physical (c + (row>>1))&3; global source pre-rotated.
// MODE 0: rect grid (XCD col-major swizzle if SWZ).
// MODE 1 (att@v, r11): UNIFORM-WINDOW scheme -- dispatch-agnostic (r9/r10
//   proved CU co-location is unpredictable: every static pairing failed).
//   Pair row-blocks (d=31-p, s=p): total work 4(d+1)+4(s+1) = 132 phases.
//   Window 0 (wi=0): row d, K[0,2112)            -> p0   (66 phases)
//   Window 1 (wi=1): row d, K[2112,(d+1)*128) -> p1, then
//                    row s, K[0,(p+1)*128)    -> p1   (66 phases total)
//   16 pairs x 8 bj x 2 windows = 256 blocks, ALL exactly 66 phases.
//   Plain fp32 stores; rows<2048 only in p1 (add2 skips p0 there).
//   Segment boundary safety: the loop's final barrier precedes both
//   epilogues; stale post-barrier LOADB racing the next segment's STAGE
//   lands in never-consumed registers; vmcnt counts remain valid (FIFO).

#define BARW() asm volatile("s_barrier" ::: "memory")
#define VMC6() asm volatile("s_waitcnt vmcnt(6)" ::: "memory")
#define LGKM0() asm volatile("s_waitcnt lgkmcnt(0)" ::: "memory")

#define STAGE(SB, KO) do { \
  u16* Lb = &LDSU[SB][0] + w * 512; \
  gld_lds16(pA0 + (KO), Lb); \
  gld_lds16(pA0 + (size_t)64 * LDA_ + (KO), Lb + 2048); \
  gld_lds16(pB0 + (KO), Lb + 4096); \
  gld_lds16(pB0 + (size_t)64 * LDB_ + (KO), Lb + 4096 + 2048); \
  gld_lds16(pB0 + (size_t)128 * LDB_ + (KO), Lb + 4096 + 4096); \
  gld_lds16(pB0 + (size_t)192 * LDB_ + (KO), Lb + 4096 + 6144); \
} while (0)

#define LOADA(BUF) do { _Pragma("unroll") \
  for (int mi = 0; mi < 8; ++mi) \
    af[mi] = *(const v8s*)(&LDSU[BUF][0] + (mi * 16 + lm) * 32 + lqs); \
} while (0)

#define LOADB(BUF) do { _Pragma("unroll") \
  for (int ni = 0; ni < 4; ++ni) \
    bf4[ni] = *(const v8s*)(&LDSU[BUF][0] + 4096 + (w * 64 + ni * 16 + lm) * 32 + lqs); \
} while (0)

template<int LDA_, int LDB_, int LDC_, int OUTMODE /*0=bf16 store, 1=fp32 store*/,
         int ADDB, int MODE, int SWZ>
__global__ __launch_bounds__(256, 2) void gemmw(
    const u16* __restrict__ A, const u16* __restrict__ B,
    void* __restrict__ Cv, int K,
    const float* __restrict__ bias, float scale) {
  int bj;
  int sI0[2], sKs[2], sKe[2];
  float* sC[2] = {nullptr, nullptr};
  int nseg;
  if (MODE == 1) {
    const int f = blockIdx.x;        // 256 blocks
    const int p = f & 15;
    bj = (f >> 4) & 7;
    const int wi = f >> 7;           // window 0 or 1
    const int d = 31 - p;
    float* p0 = (float*)Cv;
    float* p1 = p0 + (size_t)SEQ * FEAT;
    if (wi == 0) {
      nseg = 1;
      sI0[0] = d * 128; sKs[0] = 0;    sKe[0] = 2112;           sC[0] = p0;
    } else {
      nseg = 2;
      sI0[0] = d * 128; sKs[0] = 2112; sKe[0] = (d + 1) * 128;  sC[0] = p1;
      sI0[1] = p * 128; sKs[1] = 0;    sKe[1] = (p + 1) * 128;  sC[1] = p1;
    }
  } else {
    int bi;
    if (SWZ) {
      // column-major within XCD chunk: same-XCD neighbors share the B panel
      const int gx = gridDim.x, gy = gridDim.y;
      const int b = blockIdx.y * gx + blockIdx.x;
      const int cpx = (gx * gy) >> 3;            // nwg % 8 == 0
      const int s = (b & 7) * cpx + (b >> 3);
      bi = s % gy;  bj = s / gy;
    } else { bj = blockIdx.x; bi = blockIdx.y; }
    nseg = 1;
    sI0[0] = bi * 128; sKs[0] = 0; sKe[0] = K; sC[0] = nullptr;
  }
  const int j0 = bj * 256;

  // [buf][ A: 128 rows x 32 (4096 elems) | B: 256 rows x 32 (8192 elems) ]
  __shared__ u16 LDSU[3][12288];   // 72 KiB

  const int t = threadIdx.x;
  const int w = t >> 6, l = t & 63;
  const int lm = l & 15, lq = l >> 4;
  // fragment read: physical chunk = (lq + (row>>1)) & 3; row bases are
  // multiples of 8 => (row>>1)&3 == (lm>>1)&3
  const int lqs = ((lq + (lm >> 1)) & 3) * 8;

  // staging: lane l: row = base + (l>>2), physical chunk l&3,
  // logical = ((l&3)-((row>>1)&3))&3 (swizzle inverse).
  const int rA = w * 16 + (l >> 2);
  const int cA = ((((l & 3) - ((rA >> 1) & 3)) & 3)) * 8;
  const u16* pB0 = B + (size_t)(j0 + rA) * LDB_ + cA;   // fixed across segments

  auto run_seg = [&](int i0, int ks, int ke, float* Cf) {
    const u16* pA0 = A + (size_t)(i0 + rA) * LDA_ + cA;

    v4f acc[8][4];
#pragma unroll
    for (int a = 0; a < 8; ++a)
#pragma unroll
      for (int b2 = 0; b2 < 4; ++b2)
        acc[a][b2] = v4f{0.f, 0.f, 0.f, 0.f};

    v8s af[8], bf4[4];

    // prologue: stage tiles 0 (buf0) and 1 (buf1); vmcnt(6) -> tile0 landed
    STAGE(0, ks); STAGE(1, ks + 32);
    VMC6(); BARW();
    LOADB(0);                           // B fragments of tile 0 -> regs

    const int nt = (ke - ks) >> 5;      // even, >= 2 in all modes/segments
    int b0 = 0, b1 = 1;
    for (int tt = 0; tt < nt; tt += 2) {
      const int kc = ks + (tt << 5);
      const int s2 = 3 - b0 - b1;       // the third buffer
      // sub-phase 0: compute tile tt (A in b0, B preloaded in bf4)
      {
        const int kst = (kc + 64 < ke) ? kc + 64 : ks;   // A+B tile tt+2
        STAGE(s2, kst);
        LOADA(b0);
        __builtin_amdgcn_s_setprio(1);
#pragma unroll
        for (int mi = 0; mi < 8; ++mi)
#pragma unroll
          for (int ni = 0; ni < 4; ++ni)
            acc[mi][ni] = __builtin_amdgcn_mfma_f32_16x16x32_bf16(af[mi], bf4[ni], acc[mi][ni], 0, 0, 0);
        __builtin_amdgcn_s_setprio(0);
        VMC6(); BARW();                 // tile tt+1 landed (all waves)
        LOADB(b1);                      // B fragments of tile tt+1 -> regs
      }
      // sub-phase 1: compute tile tt+1 (A in b1)
      {
        const int kst = (kc + 96 < ke) ? kc + 96 : ks;   // tile tt+3 (clamped)
        STAGE(b0, kst);
        LOADA(b1);
        __builtin_amdgcn_s_setprio(1);
#pragma unroll
        for (int mi = 0; mi < 8; ++mi)
#pragma unroll
          for (int ni = 0; ni < 4; ++ni)
            acc[mi][ni] = __builtin_amdgcn_mfma_f32_16x16x32_bf16(af[mi], bf4[ni], acc[mi][ni], 0, 0, 0);
        __builtin_amdgcn_s_setprio(0);
        VMC6(); BARW();                 // tile tt+2 landed
        LOADB(s2);                      // B fragments of tile tt+2 -> regs
      }
      b1 = b0; b0 = s2;                 // bufs advance by 2 tiles
    }

    // epilogue: C/D layout col=lane&15, row=quad*4+reg [m89-verified]
#pragma unroll
    for (int mi = 0; mi < 8; ++mi) {
#pragma unroll
      for (int ni = 0; ni < 4; ++ni) {
        const int cc = j0 + w * 64 + ni * 16 + lm;
        const float badd = ADDB ? bias[cc] : 0.f;
#pragma unroll
        for (int r = 0; r < 4; ++r) {
          const int rr = i0 + mi * 16 + lq * 4 + r;
          if (OUTMODE == 0)
            ((u16*)Cv)[(size_t)rr * LDC_ + cc] = f2bf(acc[mi][ni][r] * scale + badd);
          else
            Cf[(size_t)rr * LDC_ + cc] = acc[mi][ni][r];
        }
      }
    }
  };

  run_seg(sI0[0], sKs[0], sKe[0], sC[0]);
  if (nseg == 2) run_seg(sI0[1], sKs[1], sKe[1], sC[1]);
}

#undef STAGE
#undef LOADA
#undef LOADB

// ---------- gemm8tri: 256x256 8-phase GEMM on a flat triangular grid ----------
// r1/r7-verified schedule deployed where its 1-block/CU occupancy is free:
// GEMM2's 136-block grid (0.53 rounds -> makespan = ONE block-time).
// C[M,N] = A[M,K]*B[N,K]^T, bf16, 512 thr = 8 waves (2Mx4N), wave owns 128x64,
// BK=64, double-buffered LDS 128 KiB, K % 128 == 0.
// Per K-tile: 4 quadrant phases; 1 half-tile (2 x gld_lds16) staged per phase;
// counted vmcnt(6) ONLY at phases 4/8; raw s_barrier (no drain).
// LDS swizzle: row of 64 elems = 8 chunks of 16B, logical chunk c at physical
// (c + row) & 7; global source pre-rotated (both-sides rule).

#define LDA8(BUF, MH) do { _Pragma("unroll") \
  for (int fi = 0; fi < 4; ++fi) { \
    const u16* ap = &As8[BUF][wr][(MH) * 4096 + fi * 1024]; \
    af[fi][0] = *(const v8s*)(ap + off0); \
    af[fi][1] = *(const v8s*)(ap + off1); \
  } } while (0)

#define LDB8(BUF) do { _Pragma("unroll") \
  for (int ni = 0; ni < 4; ++ni) { \
    const u16* bp = &Bs8[BUF][bh][bo + ni * 1024]; \
    bfr[ni][0] = *(const v8s*)(bp + off0); \
    bfr[ni][1] = *(const v8s*)(bp + off1); \
  } } while (0)

#define MMA8(MH, NL) do { _Pragma("unroll") \
  for (int fi = 0; fi < 4; ++fi) { _Pragma("unroll") \
    for (int nn = 0; nn < 2; ++nn) { \
      acc[(MH)*4+fi][(NL)+nn] = __builtin_amdgcn_mfma_f32_16x16x32_bf16( \
          af[fi][0], bfr[(NL)+nn][0], acc[(MH)*4+fi][(NL)+nn], 0, 0, 0); \
      acc[(MH)*4+fi][(NL)+nn] = __builtin_amdgcn_mfma_f32_16x16x32_bf16( \
          af[fi][1], bfr[(NL)+nn][1], acc[(MH)*4+fi][(NL)+nn], 0, 0, 0); \
    } } } while (0)

#define STG8A(BUF, H, KO) do { \
  gld_lds16(Ag + (size_t)(H) * 128 * LDA_ + (KO), &As8[BUF][H][w8 * 1024]); \
  gld_lds16(Ag + ((size_t)(H) * 128 + 8) * LDA_ + (KO), &As8[BUF][H][w8 * 1024 + 512]); \
  } while (0)

#define STG8B(BUF, H, KO) do { \
  gld_lds16(Bg + (size_t)(H) * 128 * LDB_ + (KO), &Bs8[BUF][H][w8 * 1024]); \
  gld_lds16(Bg + ((size_t)(H) * 128 + 8) * LDB_ + (KO), &Bs8[BUF][H][w8 * 1024 + 512]); \
  } while (0)

template<int LDA_, int LDB_, int LDC_>
__global__ __launch_bounds__(512, 2) void gemm8tri(
    const u16* __restrict__ A, const u16* __restrict__ B,
    u16* __restrict__ C, int K, float scale) {
  // flat lower-triangular grid (bj <= bi), XCD-chunked; gridDim.x % 8 == 0
  const int b = blockIdx.x;
  const int cpx = (int)gridDim.x >> 3;
  const int s = (b & 7) * cpx + (b >> 3);
  int bi = (int)((sqrtf(8.f * s + 1.f) - 1.f) * 0.5f);
  while ((bi + 1) * (bi + 2) / 2 <= s) ++bi;
  while (bi * (bi + 1) / 2 > s) --bi;
  const int bj = s - bi * (bi + 1) / 2;
  const int i0 = bi * 256, j0 = bj * 256;

  __shared__ u16 As8[2][2][8192];  // [buf][half][128*64], 64 KiB
  __shared__ u16 Bs8[2][2][8192];  // 64 KiB

  const int t = threadIdx.x;
  const int w8 = t >> 6, l = t & 63;
  const int wr = w8 >> 2, wc = w8 & 3;
  const int lm = l & 15, lq = l >> 4;
  const int bh = wc >> 1, bo = (wc & 1) * 4096;

  // fragment-read offsets within a half (chunk rotation, conflicts=0 r1)
  const int off0 = lm * 64 + ((lq + lm) & 7) * 8;        // s=0
  const int off1 = lm * 64 + ((lq + lm + 4) & 7) * 8;    // s=1

  // staging: row = w8*16 + (l>>3); logical col chunk = ((l&7) - (l>>3)) & 7
  const int srow = w8 * 16 + (l >> 3);
  const int scol = (((l & 7) - (l >> 3)) & 7) * 8;
  const u16* Ag = A + (size_t)(i0 + srow) * LDA_ + scol;
  const u16* Bg = B + (size_t)(j0 + srow) * LDB_ + scol;

  v4f acc[8][4];
#pragma unroll
  for (int a = 0; a < 8; ++a)
#pragma unroll
    for (int b2 = 0; b2 < 4; ++b2)
      acc[a][b2] = v4f{0.f, 0.f, 0.f, 0.f};

  v8s af[4][2], bfr[4][2];

  // prologue: tile0 -> buf0 (B0,B1,A0,A1), tile1 -> buf1 (B0,B1,A0).
  // 14 loads; vmcnt(6) -> oldest 8 (all of buf0) landed.
  STG8B(0, 0, 0); STG8B(0, 1, 0); STG8A(0, 0, 0); STG8A(0, 1, 0);
  STG8B(1, 0, 64); STG8B(1, 1, 64); STG8A(1, 0, 64);
  VMC6(); BARW();

  const int nit = K >> 7;  // K % 128 == 0
  for (int it = 0; it < nit; ++it) {
    const int kc = it << 7;
    const int k1 = kc + 64;                     // tile 2it+1 (always valid)
    int k2 = kc + 128; if (k2 >= K) k2 = 0;     // clamped stages never read
    int k3 = kc + 192; if (k3 >= K) k3 = 0;

    // P1: Q(m0, n0..1) on buf0
    LDA8(0, 0); LDB8(0);
    STG8A(1, 1, k1);
    BARW(); LGKM0();
    __builtin_amdgcn_s_setprio(1); MMA8(0, 0); __builtin_amdgcn_s_setprio(0);
    BARW();
    // P2: Q(m0, n2..3)
    STG8B(0, 0, k2);
    BARW();
    __builtin_amdgcn_s_setprio(1); MMA8(0, 2); __builtin_amdgcn_s_setprio(0);
    BARW();
    // P3: Q(m1, n0..1)
    LDA8(0, 1);
    STG8B(0, 1, k2);
    BARW(); LGKM0();
    __builtin_amdgcn_s_setprio(1); MMA8(1, 0); __builtin_amdgcn_s_setprio(0);
    BARW();
    // P4: Q(m1, n2..3); counted wait -> buf1 fully landed before P5
    STG8A(0, 0, k2);
    BARW();
    __builtin_amdgcn_s_setprio(1); MMA8(1, 2); __builtin_amdgcn_s_setprio(0);
    VMC6(); BARW();
    // P5: Q(m0, n0..1) on buf1
    LDA8(1, 0); LDB8(1);
    STG8A(0, 1, k2);
    BARW(); LGKM0();
    __builtin_amdgcn_s_setprio(1); MMA8(0, 0); __builtin_amdgcn_s_setprio(0);
    BARW();
    // P6: Q(m0, n2..3)
    STG8B(1, 0, k3);
    BARW();
    __builtin_amdgcn_s_setprio(1); MMA8(0, 2); __builtin_amdgcn_s_setprio(0);
    BARW();
    // P7: Q(m1, n0..1)
    LDA8(1, 1);
    STG8B(1, 1, k3);
    BARW(); LGKM0();
    __builtin_amdgcn_s_setprio(1); MMA8(1, 0); __builtin_amdgcn_s_setprio(0);
    BARW();
    // P8: Q(m1, n2..3); counted wait -> buf0 fully landed before next P1
    STG8A(1, 0, k3);
    BARW();
    __builtin_amdgcn_s_setprio(1); MMA8(1, 2); __builtin_amdgcn_s_setprio(0);
    VMC6(); BARW();
  }

  // epilogue: C/D layout col=lane&15, row=quad*4+reg [m89-verified]
#pragma unroll
  for (int mi = 0; mi < 8; ++mi) {
#pragma unroll
    for (int ni = 0; ni < 4; ++ni) {
      const int cc = j0 + wc * 64 + ni * 16 + lm;
#pragma unroll
      for (int r = 0; r < 4; ++r) {
        const int rr = i0 + wr * 128 + mi * 16 + lq * 4 + r;
        C[(size_t)rr * LDC_ + cc] = f2bf(acc[mi][ni][r] * scale);
      }
    }
  }
}

#undef LDA8
#undef LDB8
#undef MMA8
#undef STG8A
#undef STG8B

// ---------- row softmax with causal + padding mask (single bf16 input) ----------
// r11: 3-pass BRANCH-FREE form (probe: was the branchy serial online-update
// the ~70us cost?). Pass1 max via fmaxf (masked lanes -3e38); pass2
// s += expf(v - M) (masked lanes exp(-inf) = 0); pass3 store. All vectorized.
__global__ __launch_bounds__(256) void softmax_rows(
    const u16* __restrict__ S0,
    u16* __restrict__ att, const int* __restrict__ npad_p) {
  const int i = blockIdx.x;
  const int np = *npad_p;
  const int kend = ((i >> 7) + 1) << 7;   // 128-rounded: matches attV read range
  const u16* r0 = S0 + (size_t)i * SEQ;
  u16* arow = att + (size_t)i * SEQ;
  const int t = threadIdx.x;
  const int w = t >> 6, l = t & 63;
  __shared__ float sm[4], ss[4];

  // pass 1: masked max
  float m = -3.0e38f;
  for (int j0b = t * 8; j0b < kend; j0b += 2048) {
    union { u16 s8[8]; uint4 v; } ui;
    ui.v = *(const uint4*)(r0 + j0b);
#pragma unroll
    for (int q = 0; q < 8; ++q) {
      const int j = j0b + q;
      const float v = (j >= np && j <= i) ? bf2f(ui.s8[q]) : -3.0e38f;
      m = fmaxf(m, v);
    }
  }
#pragma unroll
  for (int off = 32; off > 0; off >>= 1) m = fmaxf(m, __shfl_xor(m, off));
  if (l == 0) sm[w] = m;
  __syncthreads();
  const float M = fmaxf(fmaxf(sm[0], sm[1]), fmaxf(sm[2], sm[3]));

  // pass 2: masked sum of exp(v - M)  (masked: exp(-3e38 - M) -> 0;
  // fully-masked rows: M = -3e38, sum > 0 but inv is never used)
  float s = 0.f;
  for (int j0b = t * 8; j0b < kend; j0b += 2048) {
    union { u16 s8[8]; uint4 v; } ui;
    ui.v = *(const uint4*)(r0 + j0b);
#pragma unroll
    for (int q = 0; q < 8; ++q) {
      const int j = j0b + q;
      const float v = (j >= np && j <= i) ? bf2f(ui.s8[q]) : -3.0e38f;
      s += __expf(v - M);
    }
  }
#pragma unroll
  for (int off = 32; off > 0; off >>= 1) s += __shfl_xor(s, off);
  if (l == 0) ss[w] = s;
  __syncthreads();
  const float inv = 1.f / (ss[0] + ss[1] + ss[2] + ss[3]);

  // pass 3: store normalized probabilities (padded rows -> zeros)
  for (int j0b = t * 8; j0b < kend; j0b += 2048) {
    union { u16 s8[8]; uint4 v; } ui, uo;
    ui.v = *(const uint4*)(r0 + j0b);
#pragma unroll
    for (int q = 0; q < 8; ++q) {
      const int j = j0b + q;
      float a = 0.f;
      if (j >= np && j <= i)
        a = __expf(bf2f(ui.s8[q]) - M) * inv;
      uo.s8[q] = f2bf(a);
    }
    *(uint4*)(arow + j0b) = uo.v;
  }
}

// ---------- launch ----------

extern "C" void kernel_launch(void* const* d_in, const int* in_sizes, int n_in,
                              void* d_out, int out_size, void* d_ws, size_t ws_size,
                              hipStream_t stream) {
  const float* x = (const float*)d_in[0];
  const float* W = (const float*)d_in[1];
  const float* b = (const float*)d_in[2];
  const int* npad = (const int*)d_in[3];
  float* out = (float*)d_out;

  // workspace (168 MB):
  // [xb 16MB | Wt 24MB] reused as att 32MB ][ qkvb 48MB ][ vt 16MB ]
  // [ sc0 32MB -> p0 ][ 32MB -> p1 ]  (p0/p1 contiguous; gemmw MODE1 offsets
  //                                    p1 by SEQ*FEAT floats from base)
  char* p = (char*)d_ws;
  u16* xb = (u16*)p;
  u16* Wt = (u16*)(p + (size_t)SEQ * FEAT * 2);
  u16* att = (u16*)p;
  p += (size_t)SEQ * FEAT * 2 + (size_t)F3 * FEAT * 2;
  u16* qkvb = (u16*)p;  p += (size_t)SEQ * F3 * 2;
  u16* vt   = (u16*)p;  p += (size_t)FEAT * SEQ * 2;
  u16* sc0  = (u16*)p;  p += (size_t)SEQ * SEQ * 2;   // bf16 scores -> fp32 p0
  p += (size_t)SEQ * SEQ * 2;                         // fp32 p1 (contiguous)
  if (ws_size < (size_t)(p - (char*)d_ws)) return;

  float* p0 = (float*)sc0;                    // partial window0 (32MB)
  float* p1 = p0 + (size_t)SEQ * FEAT;        // partial window1 (next 32MB)

  const float scale = 0.02209708691207961f;  // 1/sqrt(2048)

  cvt_f32_bf16<<<SEQ * FEAT / 8 / 256, 256, 0, stream>>>(x, xb, SEQ * FEAT / 8);
  transp_f2b<<<dim3(F3 / 32, FEAT / 32), dim3(32, 8), 0, stream>>>(W, F3, Wt, FEAT);
  // qkv = x @ W + b: 128x256 tiles, grid 24x32 = 768 blocks (2 blocks/CU)
  gemmw<FEAT, FEAT, F3, 0, 1, 0, 1><<<dim3(F3 / 256, SEQ / 128), 256, 0, stream>>>(
      xb, Wt, (void*)qkvb, FEAT, b, 1.0f);
  transp_b2b<<<dim3(FEAT / 32, SEQ / 32), dim3(32, 8), 0, stream>>>(
      qkvb + 2 * FEAT, F3, vt, SEQ);
  // scores = (q @ k^T)/sqrt(F): 8-phase 256^2, flat triangular grid 16*17/2 =
  // 136 blocks (1 block/CU, 0.53 rounds -> makespan = one block-time)
  gemm8tri<F3, F3, SEQ><<<dim3(136), 512, 0, stream>>>(
      qkvb, qkvb + FEAT, sc0, FEAT, scale);
  softmax_rows<<<SEQ, 256, 0, stream>>>(sc0, att, npad);
  // out = att @ v: uniform-window grid, 256 blocks x exactly 66 phases
  // (dispatch-agnostic), plain fp32 stores into p0/p1
  gemmw<SEQ, SEQ, FEAT, 1, 0, 1, 0><<<dim3(256), 256, 0, stream>>>(
      att, vt, (void*)p0, 0, nullptr, 1.0f);
  // out = p0 + p1 (rows < 2048: p1 only)
  add2_f32<<<SEQ * FEAT / 4 / 256, 256, 0, stream>>>(p0, p1, out, SEQ * FEAT / 4);
}